// Round 4
// baseline (505.871 us; speedup 1.0000x reference)
//
#include <hip/hip_runtime.h>

// ---------------------------------------------------------------------------
// LRU single step, fused, "transposed-D" MFMA orientation.
//   state = Lambda * x0 + Bn @ u          (complex; PLANAR re|im — verified R3)
//   y     = C1 @ x0_re + C2 @ x0_im + (E+D) @ u
// W as MFMA A-operand => D[row=h(or o)][col=n]; each thread owns 4 consecutive
// h/o for fixed n => all global I/O is float4, 64B-line complete.
// ---------------------------------------------------------------------------

typedef __attribute__((ext_vector_type(8))) short bf16x8;
typedef __attribute__((ext_vector_type(4))) float f32x4;
typedef unsigned short u16;
typedef unsigned int u32;

#define N_ROWS 32768
#define IN_DIM 256
#define SD 512
#define OUT_DIM 256
#define ROWS 32

__device__ float g_lam[2 * SD];                 // lam_re | lam_im
__device__ u16   g_W1[2 * SD * IN_DIM];         // [1024][256]: rows [0,512)=Bn_re, [512,1024)=Bn_im
__device__ u16   g_Wy[OUT_DIM * 1280];          // [256][1280]: cols C1 | C2 | E+D

__device__ __forceinline__ u16 f2b(float f) {
    union { float f; u32 u; } v; v.f = f;
    u32 r = v.u + 0x7FFFu + ((v.u >> 16) & 1u);   // RNE
    return (u16)(r >> 16);
}

// 8 fp32 -> bf16x8, round-half-up (adds 2^-17 rel bias; negligible here)
__device__ __forceinline__ bf16x8 pack8(float4 f0, float4 f1) {
    union { float4 f; u32 u[4]; } a, b;
    a.f = f0; b.f = f1;
    union { u32 u[4]; bf16x8 v; } r;
    r.u[0] = ((a.u[0] + 0x8000u) >> 16) | ((a.u[1] + 0x8000u) & 0xFFFF0000u);
    r.u[1] = ((a.u[2] + 0x8000u) >> 16) | ((a.u[3] + 0x8000u) & 0xFFFF0000u);
    r.u[2] = ((b.u[0] + 0x8000u) >> 16) | ((b.u[1] + 0x8000u) & 0xFFFF0000u);
    r.u[3] = ((b.u[2] + 0x8000u) >> 16) | ((b.u[3] + 0x8000u) & 0xFFFF0000u);
    return r.v;
}

// --- single fused prep kernel (all branches independent, block-uniform) -----
__global__ __launch_bounds__(256) void prep_all(
    const float* __restrict__ nu_log, const float* __restrict__ theta_log,
    const float* __restrict__ gamma_log,
    const float* __restrict__ B_re, const float* __restrict__ B_im,
    const float* __restrict__ C_re, const float* __restrict__ C_im,
    const float* __restrict__ D)
{
    __shared__ float s_gg[SD];
    const int bid = blockIdx.x;
    const int tid = threadIdx.x;

    if (bid < 1024) {                       // W1 = Bn planar bf16
        int idx = bid * 256 + tid;
        int r = idx >> 8, k = idx & 255;
        int h = r & 511;
        float g = expf(gamma_log[h]);
        const float* src = (r < 512) ? B_re : B_im;
        g_W1[idx] = f2b(src[h * IN_DIM + k] * g);
    } else if (bid < 2048) {                // Wy cols [0,1024): C1 | C2
        int idx = (bid - 1024) * 256 + tid;
        int o = idx >> 10, c = idx & 1023;
        int h = c & 511;
        float mod = expf(-expf(nu_log[h]));
        float th  = expf(theta_log[h]);
        float lre = mod * cosf(th), lim = mod * sinf(th);
        float cr = C_re[o*SD + h], ci = C_im[o*SD + h];
        float v = (c < 512) ? (cr*lre - ci*lim) : (-(cr*lim + ci*lre));
        g_Wy[(size_t)o*1280 + c] = f2b(v);
    } else if (bid < 2304) {                // Wy cols [1024,1280): E + D
        for (int i = tid; i < SD; i += 256) s_gg[i] = expf(gamma_log[i]);
        __syncthreads();
        int idx = (bid - 2048) * 256 + tid;
        int o = idx >> 8, j = idx & 255;
        float a0=0.f, a1=0.f, a2=0.f, a3=0.f;
        for (int h = 0; h < SD; h += 4) {
            a0 += (C_re[o*SD+h  ]*B_re[(h  )*IN_DIM+j] - C_im[o*SD+h  ]*B_im[(h  )*IN_DIM+j]) * s_gg[h  ];
            a1 += (C_re[o*SD+h+1]*B_re[(h+1)*IN_DIM+j] - C_im[o*SD+h+1]*B_im[(h+1)*IN_DIM+j]) * s_gg[h+1];
            a2 += (C_re[o*SD+h+2]*B_re[(h+2)*IN_DIM+j] - C_im[o*SD+h+2]*B_im[(h+2)*IN_DIM+j]) * s_gg[h+2];
            a3 += (C_re[o*SD+h+3]*B_re[(h+3)*IN_DIM+j] - C_im[o*SD+h+3]*B_im[(h+3)*IN_DIM+j]) * s_gg[h+3];
        }
        g_Wy[(size_t)o*1280 + 1024 + j] = f2b(((a0+a1)+(a2+a3)) + D[o*IN_DIM+j]);
    } else {                                // lam for main epilogue
        for (int i = tid; i < SD; i += 256) {
            float mod = expf(-expf(nu_log[i]));
            float th  = expf(theta_log[i]);
            g_lam[i]      = mod * cosf(th);
            g_lam[SD + i] = mod * sinf(th);
        }
    }
}

// --- main fused kernel ------------------------------------------------------
__global__ __launch_bounds__(256) void lru_main(
    const float* __restrict__ u, const float* __restrict__ x0_re,
    const float* __restrict__ x0_im,
    float* __restrict__ y_out, float* __restrict__ st_out,
    long long st_limit)
{
    __shared__ u16 Xu[ROWS * 264];      // u tile bf16, stride 264 (16B-aligned rows)
    __shared__ float lamL[1024];

    const int tid  = threadIdx.x;
    const int wv   = tid >> 6;
    const int lane = tid & 63;
    const int quad = lane >> 4;
    const int l16  = lane & 15;
    const int kq   = quad * 8;
    const size_t n0 = (size_t)blockIdx.x * ROWS;

    for (int i = tid; i < 1024; i += 256) lamL[i] = g_lam[i];
    for (int i = tid; i < ROWS * 64; i += 256) {
        int r = i >> 6, c4 = i & 63;
        float4 v = ((const float4*)(u + (n0 + r) * IN_DIM))[c4];
        ushort4 b;
        b.x = f2b(v.x); b.y = f2b(v.y); b.z = f2b(v.z); b.w = f2b(v.w);
        *(ushort4*)(&Xu[r * 264 + c4 * 4]) = b;
    }
    __syncthreads();

    const bool full = (st_limit >= (long long)N_ROWS * 1024);

    // ---------------- Phase A: state (re+im fused per h-range) -------------
    for (int s = 0; s < 2; ++s) {
        const int hbase = s * 256 + wv * 64;
        f32x4 ar[4][2], ai[4][2];
        #pragma unroll
        for (int ht = 0; ht < 4; ++ht)
            #pragma unroll
            for (int nt = 0; nt < 2; ++nt) {
                ar[ht][nt] = f32x4{0.f,0.f,0.f,0.f};
                ai[ht][nt] = f32x4{0.f,0.f,0.f,0.f};
            }

        #pragma unroll 2
        for (int k0 = 0; k0 < IN_DIM; k0 += 32) {
            bf16x8 bu[2];
            bu[0] = *(const bf16x8*)(&Xu[l16 * 264 + k0 + kq]);
            bu[1] = *(const bf16x8*)(&Xu[(16 + l16) * 264 + k0 + kq]);
            bf16x8 wre[4], wim[4];
            #pragma unroll
            for (int ht = 0; ht < 4; ++ht) {
                const size_t row = (size_t)(hbase + ht * 16 + l16);
                wre[ht] = *(const bf16x8*)(g_W1 + row * IN_DIM + k0 + kq);
                wim[ht] = *(const bf16x8*)(g_W1 + (row + 512) * IN_DIM + k0 + kq);
            }
            #pragma unroll
            for (int ht = 0; ht < 4; ++ht)
                #pragma unroll
                for (int nt = 0; nt < 2; ++nt) {
                    ar[ht][nt] = __builtin_amdgcn_mfma_f32_16x16x32_bf16(wre[ht], bu[nt], ar[ht][nt], 0, 0, 0);
                    ai[ht][nt] = __builtin_amdgcn_mfma_f32_16x16x32_bf16(wim[ht], bu[nt], ai[ht][nt], 0, 0, 0);
                }
        }

        // epilogue: fully-vectorized, x0 read once, both planes written
        #pragma unroll
        for (int ht = 0; ht < 4; ++ht) {
            const int h0 = hbase + ht * 16 + quad * 4;
            const float4 lr4 = *(const float4*)(&lamL[h0]);
            const float4 li4 = *(const float4*)(&lamL[512 + h0]);
            #pragma unroll
            for (int nt = 0; nt < 2; ++nt) {
                const size_t n = n0 + nt * 16 + l16;
                const float4 xr = *(const float4*)(x0_re + n * SD + h0);
                const float4 xi = *(const float4*)(x0_im + n * SD + h0);
                float4 sre, sim;
                sre.x = fmaf(lr4.x, xr.x, fmaf(-li4.x, xi.x, ar[ht][nt][0]));
                sre.y = fmaf(lr4.y, xr.y, fmaf(-li4.y, xi.y, ar[ht][nt][1]));
                sre.z = fmaf(lr4.z, xr.z, fmaf(-li4.z, xi.z, ar[ht][nt][2]));
                sre.w = fmaf(lr4.w, xr.w, fmaf(-li4.w, xi.w, ar[ht][nt][3]));
                sim.x = fmaf(lr4.x, xi.x, fmaf(li4.x, xr.x, ai[ht][nt][0]));
                sim.y = fmaf(lr4.y, xi.y, fmaf(li4.y, xr.y, ai[ht][nt][1]));
                sim.z = fmaf(lr4.z, xi.z, fmaf(li4.z, xr.z, ai[ht][nt][2]));
                sim.w = fmaf(lr4.w, xi.w, fmaf(li4.w, xr.w, ai[ht][nt][3]));
                if (full) {
                    *(float4*)(st_out + n * SD + h0) = sre;
                    *(float4*)(st_out + (size_t)N_ROWS * SD + n * SD + h0) = sim;
                } else {
                    float srev[4] = {sre.x, sre.y, sre.z, sre.w};
                    float simv[4] = {sim.x, sim.y, sim.z, sim.w};
                    for (int j = 0; j < 4; ++j) {
                        long long ir = (long long)n * SD + h0 + j;
                        long long ii = (long long)N_ROWS * SD + ir;
                        if (ir < st_limit) st_out[ir] = srev[j];
                        if (ii < st_limit) st_out[ii] = simv[j];
                    }
                }
            }
        }
    }

    // ---------------- Phase B: y ------------------------------------------
    f32x4 ay[4][2];
    #pragma unroll
    for (int ot = 0; ot < 4; ++ot)
        #pragma unroll
        for (int nt = 0; nt < 2; ++nt)
            ay[ot][nt] = f32x4{0.f,0.f,0.f,0.f};

    #pragma unroll 1
    for (int part = 0; part < 2; ++part) {
        const float* __restrict__ xp = part ? x0_im : x0_re;
        const int kb = part * 512;
        #pragma unroll 2
        for (int k0 = 0; k0 < SD; k0 += 32) {
            bf16x8 a[4], b[2];
            #pragma unroll
            for (int ot = 0; ot < 4; ++ot)
                a[ot] = *(const bf16x8*)(g_Wy + (size_t)(wv*64 + ot*16 + l16) * 1280 + kb + k0 + kq);
            #pragma unroll
            for (int nt = 0; nt < 2; ++nt) {
                const float* p = xp + (n0 + nt*16 + l16) * SD + k0 + kq;
                b[nt] = pack8(*(const float4*)p, *(const float4*)(p + 4));
            }
            #pragma unroll
            for (int ot = 0; ot < 4; ++ot)
                #pragma unroll
                for (int nt = 0; nt < 2; ++nt)
                    ay[ot][nt] = __builtin_amdgcn_mfma_f32_16x16x32_bf16(a[ot], b[nt], ay[ot][nt], 0, 0, 0);
        }
    }
    // u chunk from LDS (same b-fragments as phase A)
    #pragma unroll 2
    for (int k0 = 0; k0 < IN_DIM; k0 += 32) {
        bf16x8 a[4], b[2];
        b[0] = *(const bf16x8*)(&Xu[l16 * 264 + k0 + kq]);
        b[1] = *(const bf16x8*)(&Xu[(16 + l16) * 264 + k0 + kq]);
        #pragma unroll
        for (int ot = 0; ot < 4; ++ot)
            a[ot] = *(const bf16x8*)(g_Wy + (size_t)(wv*64 + ot*16 + l16) * 1280 + 1024 + k0 + kq);
        #pragma unroll
        for (int ot = 0; ot < 4; ++ot)
            #pragma unroll
            for (int nt = 0; nt < 2; ++nt)
                ay[ot][nt] = __builtin_amdgcn_mfma_f32_16x16x32_bf16(a[ot], b[nt], ay[ot][nt], 0, 0, 0);
    }
    // y epilogue: float4 stores
    #pragma unroll
    for (int ot = 0; ot < 4; ++ot)
        #pragma unroll
        for (int nt = 0; nt < 2; ++nt) {
            const size_t n = n0 + nt * 16 + l16;
            const int o = wv * 64 + ot * 16 + quad * 4;
            float4 v;
            v.x = ay[ot][nt][0]; v.y = ay[ot][nt][1];
            v.z = ay[ot][nt][2]; v.w = ay[ot][nt][3];
            *(float4*)(y_out + n * OUT_DIM + o) = v;
        }
}

extern "C" void kernel_launch(void* const* d_in, const int* in_sizes, int n_in,
                              void* d_out, int out_size, void* d_ws, size_t ws_size,
                              hipStream_t stream) {
    const float* u         = (const float*)d_in[0];
    const float* x0_re     = (const float*)d_in[1];
    const float* x0_im     = (const float*)d_in[2];
    const float* nu_log    = (const float*)d_in[3];
    const float* theta_log = (const float*)d_in[4];
    const float* gamma_log = (const float*)d_in[5];
    const float* B_re      = (const float*)d_in[6];
    const float* B_im      = (const float*)d_in[7];
    const float* C_re      = (const float*)d_in[8];
    const float* C_im      = (const float*)d_in[9];
    const float* D         = (const float*)d_in[10];

    float* y_out  = (float*)d_out;
    float* st_out = y_out + (size_t)N_ROWS * OUT_DIM;
    long long st_limit = (long long)out_size - (long long)N_ROWS * OUT_DIM;

    prep_all<<<2305, 256, 0, stream>>>(nu_log, theta_log, gamma_log,
                                       B_re, B_im, C_re, C_im, D);
    lru_main<<<N_ROWS / ROWS, 256, 0, stream>>>(u, x0_re, x0_im, y_out, st_out, st_limit);
}